// Round 1
// baseline (620.885 us; speedup 1.0000x reference)
//
#include <hip/hip_runtime.h>
#include <stdint.h>

typedef unsigned short u16;
typedef __bf16 bf8v __attribute__((ext_vector_type(8)));
typedef float f4v __attribute__((ext_vector_type(4)));

__device__ __forceinline__ u16 f2bf(float f) {
  uint32_t x = __float_as_uint(f);
  return (u16)((x + 0x7FFFu + ((x >> 16) & 1u)) >> 16);  // RNE, inputs are finite
}

// async global->LDS, 16B/lane, dest = wave-uniform base + lane*16
#define GLDS16(gp, lp)                                                        \
  __builtin_amdgcn_global_load_lds(                                           \
      (const __attribute__((address_space(1))) void*)(const void*)(gp),       \
      (__attribute__((address_space(3))) void*)(void*)(lp), 16, 0, 0)

// ---------------------------------------------------------------- cast fp32->bf16
__global__ __launch_bounds__(256) void k_cvt_act(const float* __restrict__ Q,
                                                 const float* __restrict__ K,
                                                 const float* __restrict__ V,
                                                 u16* __restrict__ Qb,
                                                 u16* __restrict__ Kb,
                                                 u16* __restrict__ Vb) {
  const float* src = blockIdx.z == 0 ? Q : (blockIdx.z == 1 ? K : V);
  u16* dst = blockIdx.z == 0 ? Qb : (blockIdx.z == 1 ? Kb : Vb);
  size_t i = ((size_t)blockIdx.x * 256 + threadIdx.x) * 4;
  float4 v = *(const float4*)(src + i);
  ushort4 o;
  o.x = f2bf(v.x); o.y = f2bf(v.y); o.z = f2bf(v.z); o.w = f2bf(v.w);
  *(ushort4*)(dst + i) = o;
}

// ------------------------------------------ transpose + cast weights: W[k][n] -> WT[n][k] bf16
__global__ __launch_bounds__(256) void k_cvt_w(const float* __restrict__ W0, const float* __restrict__ W1,
                                               const float* __restrict__ W2, const float* __restrict__ W3,
                                               u16* __restrict__ T0, u16* __restrict__ T1,
                                               u16* __restrict__ T2, u16* __restrict__ T3) {
  int z = blockIdx.z;
  const float* W = z == 0 ? W0 : z == 1 ? W1 : z == 2 ? W2 : W3;
  u16* T = z == 0 ? T0 : z == 1 ? T1 : z == 2 ? T2 : T3;
  __shared__ float tile[64][65];
  int n0 = blockIdx.x * 64, k0 = blockIdx.y * 64;
  int t = threadIdx.x;
#pragma unroll
  for (int i = 0; i < 16; ++i) {
    int idx = i * 256 + t;
    int rk = idx >> 6, cn = idx & 63;
    tile[rk][cn] = W[(size_t)(k0 + rk) * 1024 + n0 + cn];
  }
  __syncthreads();
#pragma unroll
  for (int i = 0; i < 16; ++i) {
    int idx = i * 256 + t;
    int rn = idx >> 6, ck = idx & 63;
    T[(size_t)(n0 + rn) * 1024 + k0 + ck] = f2bf(tile[ck][rn]);
  }
}

// ---------------------------------------------------------------- fused QKV projection GEMM
// A[4096][1024] bf16 @ WT[1024(n)][1024(k)] bf16 -> q/k: [b,h,s,64] bf16, v: [b,h,64,s] bf16
__global__ __launch_bounds__(256) void k_proj(const u16* __restrict__ Qb, const u16* __restrict__ Kb,
                                              const u16* __restrict__ Vb,
                                              const u16* __restrict__ WqT, const u16* __restrict__ WkT,
                                              const u16* __restrict__ WvT,
                                              const float* __restrict__ bq, const float* __restrict__ bk,
                                              const float* __restrict__ bv,
                                              u16* __restrict__ qh, u16* __restrict__ kh,
                                              u16* __restrict__ vT) {
  int z = blockIdx.z;
  const u16* A = z == 0 ? Qb : z == 1 ? Kb : Vb;
  const u16* Bt = z == 0 ? WqT : z == 1 ? WkT : WvT;
  const float* bias = z == 0 ? bq : z == 1 ? bk : bv;
  u16* out = z == 0 ? qh : z == 1 ? kh : vT;
  bool vtrans = (z == 2);

  __shared__ __align__(16) u16 sA[128 * 64];
  __shared__ __align__(16) u16 sB[128 * 64];

  int m0 = blockIdx.y * 128, n0 = blockIdx.x * 128;
  int t = threadIdx.x, w = t >> 6, lane = t & 63;
  int col = lane & 15, quad = lane >> 4;

  f4v zero4 = {0.f, 0.f, 0.f, 0.f};
  f4v acc[2][8];
#pragma unroll
  for (int tm = 0; tm < 2; ++tm)
#pragma unroll
    for (int tn = 0; tn < 8; ++tn) acc[tm][tn] = zero4;

  for (int kt = 0; kt < 1024; kt += 64) {
#pragma unroll
    for (int i = 0; i < 4; ++i) {
      int seg = i * 4 + w;
      int e = seg * 512 + lane * 8;
      int r = e >> 6, c = e & 63;
      GLDS16(A + (size_t)(m0 + r) * 1024 + kt + c, sA + seg * 512);
      GLDS16(Bt + (size_t)(n0 + r) * 1024 + kt + c, sB + seg * 512);
    }
    __syncthreads();
#pragma unroll
    for (int ks = 0; ks < 2; ++ks) {
      bf8v af[2], bfr[8];
#pragma unroll
      for (int tm = 0; tm < 2; ++tm)
        af[tm] = *(const bf8v*)&sA[(w * 32 + tm * 16 + col) * 64 + ks * 32 + quad * 8];
#pragma unroll
      for (int tn = 0; tn < 8; ++tn)
        bfr[tn] = *(const bf8v*)&sB[(tn * 16 + col) * 64 + ks * 32 + quad * 8];
#pragma unroll
      for (int tm = 0; tm < 2; ++tm)
#pragma unroll
        for (int tn = 0; tn < 8; ++tn)
          acc[tm][tn] = __builtin_amdgcn_mfma_f32_16x16x32_bf16(af[tm], bfr[tn], acc[tm][tn], 0, 0, 0);
    }
    __syncthreads();
  }

#pragma unroll
  for (int tm = 0; tm < 2; ++tm)
#pragma unroll
    for (int tn = 0; tn < 8; ++tn)
#pragma unroll
      for (int r = 0; r < 4; ++r) {
        int gr = m0 + w * 32 + tm * 16 + quad * 4 + r;
        int gc = n0 + tn * 16 + col;
        float v = acc[tm][tn][r] + bias[gc];
        int b = gr >> 10, s = gr & 1023;
        int h = gc >> 6, d = gc & 63;
        size_t off = vtrans ? ((size_t)((b * 16 + h) * 64 + d) * 1024 + s)
                            : ((size_t)((b * 16 + h) * 1024 + s) * 64 + d);
        out[off] = f2bf(v);
      }
}

// ---------------------------------------------------------------- attention pass A:
// raw scores (scaled+masked) -> d_out attn region (fp32 scratch), row max/sumexp -> stats
__global__ __launch_bounds__(256) void k_attnA(const u16* __restrict__ qh, const u16* __restrict__ kh,
                                               const unsigned char* __restrict__ mask,
                                               float* __restrict__ attn,
                                               float* __restrict__ statM, float* __restrict__ statL) {
  int qt = blockIdx.x, bh = blockIdx.y;
  int b = bh >> 4;
  __shared__ __align__(16) u16 sQ[128 * 64];
  __shared__ __align__(16) u16 sK[128 * 64];
  __shared__ __align__(16) unsigned char sM[128 * 128];
  int t = threadIdx.x, w = t >> 6, lane = t & 63;
  int col = lane & 15, quad = lane >> 4;

  {
    const u16* qbase = qh + ((size_t)bh * 1024 + qt * 128) * 64;
#pragma unroll
    for (int i = 0; i < 4; ++i) {
      int seg = i * 4 + w;
      GLDS16(qbase + seg * 512 + lane * 8, sQ + seg * 512);
    }
  }

  float mrun[2][4], lrun[2][4];
#pragma unroll
  for (int tm = 0; tm < 2; ++tm)
#pragma unroll
    for (int r = 0; r < 4; ++r) { mrun[tm][r] = -3.0e38f; lrun[tm][r] = 0.f; }

  f4v zero4 = {0.f, 0.f, 0.f, 0.f};

  for (int nc = 0; nc < 8; ++nc) {
    const u16* kbase = kh + ((size_t)bh * 1024 + nc * 128) * 64;
#pragma unroll
    for (int i = 0; i < 4; ++i) {
      int seg = i * 4 + w;
      GLDS16(kbase + seg * 512 + lane * 8, sK + seg * 512);
    }
    const unsigned char* mbase = mask + (size_t)b * 1024 * 1024 + (size_t)(qt * 128) * 1024 + nc * 128;
#pragma unroll
    for (int i = 0; i < 4; ++i) {
      int seg = i * 4 + w;
      int e = seg * 1024 + lane * 16;
      int r = e >> 7, c = e & 127;
      GLDS16(mbase + (size_t)r * 1024 + c, sM + seg * 1024);
    }
    __syncthreads();

    f4v acc[2][8];
#pragma unroll
    for (int tm = 0; tm < 2; ++tm)
#pragma unroll
      for (int tn = 0; tn < 8; ++tn) acc[tm][tn] = zero4;

#pragma unroll
    for (int ks = 0; ks < 2; ++ks) {
      bf8v af[2], bfr[8];
#pragma unroll
      for (int tm = 0; tm < 2; ++tm)
        af[tm] = *(const bf8v*)&sQ[(w * 32 + tm * 16 + col) * 64 + ks * 32 + quad * 8];
#pragma unroll
      for (int tn = 0; tn < 8; ++tn)
        bfr[tn] = *(const bf8v*)&sK[(tn * 16 + col) * 64 + ks * 32 + quad * 8];
#pragma unroll
      for (int tm = 0; tm < 2; ++tm)
#pragma unroll
        for (int tn = 0; tn < 8; ++tn)
          acc[tm][tn] = __builtin_amdgcn_mfma_f32_16x16x32_bf16(af[tm], bfr[tn], acc[tm][tn], 0, 0, 0);
    }

#pragma unroll
    for (int tm = 0; tm < 2; ++tm)
#pragma unroll
      for (int r = 0; r < 4; ++r) {
        int lrow = w * 32 + tm * 16 + quad * 4 + r;
        float vals[8];
        float cmax = -3.0e38f;
#pragma unroll
        for (int tn = 0; tn < 8; ++tn) {
          float v = acc[tm][tn][r] * 0.125f;
          if (sM[lrow * 128 + tn * 16 + col]) v = -1e9f;
          vals[tn] = v;
          cmax = fmaxf(cmax, v);
        }
#pragma unroll
        for (int off = 1; off < 16; off <<= 1) cmax = fmaxf(cmax, __shfl_xor(cmax, off));
        float csum = 0.f;
#pragma unroll
        for (int tn = 0; tn < 8; ++tn) csum += __expf(vals[tn] - cmax);
#pragma unroll
        for (int off = 1; off < 16; off <<= 1) csum += __shfl_xor(csum, off);
        float mo = mrun[tm][r];
        float mn = fmaxf(mo, cmax);
        lrun[tm][r] = lrun[tm][r] * __expf(mo - mn) + csum * __expf(cmax - mn);
        mrun[tm][r] = mn;
        float* arow = attn + ((size_t)bh * 1024 + (size_t)qt * 128 + lrow) * 1024 + nc * 128;
#pragma unroll
        for (int tn = 0; tn < 8; ++tn) arow[tn * 16 + col] = vals[tn];
      }
    __syncthreads();
  }

  if (col == 0) {
#pragma unroll
    for (int tm = 0; tm < 2; ++tm)
#pragma unroll
      for (int r = 0; r < 4; ++r) {
        size_t idx = (size_t)bh * 1024 + qt * 128 + w * 32 + tm * 16 + quad * 4 + r;
        statM[idx] = mrun[tm][r];
        statL[idx] = lrun[tm][r];
      }
  }
}

// ---------------------------------------------------------------- attention pass B:
// normalize -> final attn probs (in place), P@V -> ctx [4096][1024] bf16
__global__ __launch_bounds__(256) void k_attnB(const u16* __restrict__ vT,
                                               const float* __restrict__ statM,
                                               const float* __restrict__ statL,
                                               float* __restrict__ attn, u16* __restrict__ ctx) {
  int qt = blockIdx.x, bh = blockIdx.y, b = bh >> 4, h = bh & 15;
  __shared__ __align__(16) u16 sP[128 * 128];
  __shared__ __align__(16) u16 sV[64 * 128];
  int t = threadIdx.x, w = t >> 6, lane = t & 63;
  int col = lane & 15, quad = lane >> 4;

  float m_r[2][4], linv[2][4];
#pragma unroll
  for (int tm = 0; tm < 2; ++tm)
#pragma unroll
    for (int r = 0; r < 4; ++r) {
      size_t idx = (size_t)bh * 1024 + qt * 128 + w * 32 + tm * 16 + quad * 4 + r;
      m_r[tm][r] = statM[idx];
      linv[tm][r] = 1.0f / statL[idx];
    }

  f4v zero4 = {0.f, 0.f, 0.f, 0.f};
  f4v acc[2][4];
#pragma unroll
  for (int tm = 0; tm < 2; ++tm)
#pragma unroll
    for (int tn = 0; tn < 4; ++tn) acc[tm][tn] = zero4;

  for (int kc = 0; kc < 8; ++kc) {
    // 1) read raw scores, compute p, write final probs back (fp32)
    float pv[2][4][8];
#pragma unroll
    for (int tm = 0; tm < 2; ++tm)
#pragma unroll
      for (int r = 0; r < 4; ++r) {
        float* arow = attn + ((size_t)bh * 1024 + (size_t)qt * 128 + w * 32 + tm * 16 + quad * 4 + r) * 1024 + kc * 128;
#pragma unroll
        for (int tn = 0; tn < 8; ++tn) {
          float s = arow[tn * 16 + col];
          float p = __expf(s - m_r[tm][r]) * linv[tm][r];
          arow[tn * 16 + col] = p;
          pv[tm][r][tn] = p;
        }
      }
    __syncthreads();  // previous iter's MFMAs done -> sP/sV free
    // 2) stage V chunk (async) + write P tile
    const u16* vbase = vT + (size_t)bh * 64 * 1024 + kc * 128;
#pragma unroll
    for (int i = 0; i < 4; ++i) {
      int seg = i * 4 + w;
      int e = seg * 512 + lane * 8;
      GLDS16(vbase + (size_t)(e >> 7) * 1024 + (e & 127), sV + seg * 512);
    }
#pragma unroll
    for (int tm = 0; tm < 2; ++tm)
#pragma unroll
      for (int r = 0; r < 4; ++r)
#pragma unroll
        for (int tn = 0; tn < 8; ++tn)
          sP[(w * 32 + tm * 16 + quad * 4 + r) * 128 + tn * 16 + col] = f2bf(pv[tm][r][tn]);
    __syncthreads();  // sP visible, vmcnt drained -> sV ready
    // 3) P @ V
#pragma unroll
    for (int ks = 0; ks < 4; ++ks) {
      bf8v af[2], bfr[4];
#pragma unroll
      for (int tm = 0; tm < 2; ++tm)
        af[tm] = *(const bf8v*)&sP[(w * 32 + tm * 16 + col) * 128 + ks * 32 + quad * 8];
#pragma unroll
      for (int tn = 0; tn < 4; ++tn)
        bfr[tn] = *(const bf8v*)&sV[(tn * 16 + col) * 128 + ks * 32 + quad * 8];
#pragma unroll
      for (int tm = 0; tm < 2; ++tm)
#pragma unroll
        for (int tn = 0; tn < 4; ++tn)
          acc[tm][tn] = __builtin_amdgcn_mfma_f32_16x16x32_bf16(af[tm], bfr[tn], acc[tm][tn], 0, 0, 0);
    }
  }

#pragma unroll
  for (int tm = 0; tm < 2; ++tm)
#pragma unroll
    for (int tn = 0; tn < 4; ++tn)
#pragma unroll
      for (int r = 0; r < 4; ++r) {
        int token = qt * 128 + w * 32 + tm * 16 + quad * 4 + r;
        ctx[(size_t)(b * 1024 + token) * 1024 + h * 64 + tn * 16 + col] = f2bf(acc[tm][tn][r]);
      }
}

// ---------------------------------------------------------------- out projection + residual
__global__ __launch_bounds__(256) void k_outproj(const u16* __restrict__ ctx, const u16* __restrict__ WoT,
                                                 const float* __restrict__ bout,
                                                 const float* __restrict__ Qres, float* __restrict__ y) {
  __shared__ __align__(16) u16 sA[128 * 64];
  __shared__ __align__(16) u16 sB[128 * 64];
  int m0 = blockIdx.y * 128, n0 = blockIdx.x * 128;
  int t = threadIdx.x, w = t >> 6, lane = t & 63;
  int col = lane & 15, quad = lane >> 4;

  f4v zero4 = {0.f, 0.f, 0.f, 0.f};
  f4v acc[2][8];
#pragma unroll
  for (int tm = 0; tm < 2; ++tm)
#pragma unroll
    for (int tn = 0; tn < 8; ++tn) acc[tm][tn] = zero4;

  for (int kt = 0; kt < 1024; kt += 64) {
#pragma unroll
    for (int i = 0; i < 4; ++i) {
      int seg = i * 4 + w;
      int e = seg * 512 + lane * 8;
      int r = e >> 6, c = e & 63;
      GLDS16(ctx + (size_t)(m0 + r) * 1024 + kt + c, sA + seg * 512);
      GLDS16(WoT + (size_t)(n0 + r) * 1024 + kt + c, sB + seg * 512);
    }
    __syncthreads();
#pragma unroll
    for (int ks = 0; ks < 2; ++ks) {
      bf8v af[2], bfr[8];
#pragma unroll
      for (int tm = 0; tm < 2; ++tm)
        af[tm] = *(const bf8v*)&sA[(w * 32 + tm * 16 + col) * 64 + ks * 32 + quad * 8];
#pragma unroll
      for (int tn = 0; tn < 8; ++tn)
        bfr[tn] = *(const bf8v*)&sB[(tn * 16 + col) * 64 + ks * 32 + quad * 8];
#pragma unroll
      for (int tm = 0; tm < 2; ++tm)
#pragma unroll
        for (int tn = 0; tn < 8; ++tn)
          acc[tm][tn] = __builtin_amdgcn_mfma_f32_16x16x32_bf16(af[tm], bfr[tn], acc[tm][tn], 0, 0, 0);
    }
    __syncthreads();
  }

#pragma unroll
  for (int tm = 0; tm < 2; ++tm)
#pragma unroll
    for (int tn = 0; tn < 8; ++tn)
#pragma unroll
      for (int r = 0; r < 4; ++r) {
        int gr = m0 + w * 32 + tm * 16 + quad * 4 + r;
        int gc = n0 + tn * 16 + col;
        float v = acc[tm][tn][r] + bout[gc] + Qres[(size_t)gr * 1024 + gc];
        y[(size_t)gr * 1024 + gc] = v;
      }
}

// ---------------------------------------------------------------- layernorm
__global__ __launch_bounds__(256) void k_ln(const float* __restrict__ y, const float* __restrict__ g,
                                            const float* __restrict__ bb, float* __restrict__ out) {
  int r = blockIdx.x, t = threadIdx.x;
  const float* row = y + (size_t)r * 1024;
  float4 v = ((const float4*)row)[t];
  float s = v.x + v.y + v.z + v.w;
  float sq = v.x * v.x + v.y * v.y + v.z * v.z + v.w * v.w;
#pragma unroll
  for (int off = 1; off < 64; off <<= 1) {
    s += __shfl_xor(s, off);
    sq += __shfl_xor(sq, off);
  }
  __shared__ float ss[4], ssq[4];
  if ((t & 63) == 0) { ss[t >> 6] = s; ssq[t >> 6] = sq; }
  __syncthreads();
  s = ss[0] + ss[1] + ss[2] + ss[3];
  sq = ssq[0] + ssq[1] + ssq[2] + ssq[3];
  float mu = s * (1.f / 1024.f);
  float var = sq * (1.f / 1024.f) - mu * mu;
  float rst = rsqrtf(var + 1e-5f);
  float4 gg = ((const float4*)g)[t];
  float4 bv = ((const float4*)bb)[t];
  float4 o;
  o.x = (v.x - mu) * rst * gg.x + bv.x;
  o.y = (v.y - mu) * rst * gg.y + bv.y;
  o.z = (v.z - mu) * rst * gg.z + bv.z;
  o.w = (v.w - mu) * rst * gg.w + bv.w;
  ((float4*)(out + (size_t)r * 1024))[t] = o;
}

extern "C" void kernel_launch(void* const* d_in, const int* in_sizes, int n_in,
                              void* d_out, int out_size, void* d_ws, size_t ws_size,
                              hipStream_t stream) {
  (void)in_sizes; (void)n_in; (void)out_size; (void)ws_size;
  const float* Q = (const float*)d_in[0];
  const float* K = (const float*)d_in[1];
  const float* V = (const float*)d_in[2];
  const unsigned char* mask = (const unsigned char*)d_in[3];
  const float* Wq = (const float*)d_in[4];
  const float* bq = (const float*)d_in[5];
  const float* Wk = (const float*)d_in[6];
  const float* bk = (const float*)d_in[7];
  const float* Wv = (const float*)d_in[8];
  const float* bv = (const float*)d_in[9];
  const float* Wout = (const float*)d_in[10];
  const float* bout = (const float*)d_in[11];
  const float* lng = (const float*)d_in[12];
  const float* lnb = (const float*)d_in[13];

  u16* Qb = (u16*)d_ws;              // [4096][1024] bf16
  u16* Kb = Qb + 4194304;
  u16* Vb = Kb + 4194304;
  u16* WqT = Vb + 4194304;           // [1024][1024] bf16 (transposed)
  u16* WkT = WqT + 1048576;
  u16* WvT = WkT + 1048576;
  u16* WoT = WvT + 1048576;
  u16* qh = WoT + 1048576;           // [b,h,s,64] bf16
  u16* kh = qh + 4194304;            // [b,h,s,64]
  u16* vT = kh + 4194304;            // [b,h,64,s]
  u16* ctx = vT + 4194304;           // [4096][1024] bf16
  float* statM = (float*)(ctx + 4194304);
  float* statL = statM + 65536;
  float* y = statL + 65536;          // [4096][1024] f32

  float* outp = (float*)d_out;
  float* attn = outp + 4194304;      // [4][16][1024][1024] f32

  k_cvt_act<<<dim3(4096, 1, 3), 256, 0, stream>>>(Q, K, V, Qb, Kb, Vb);
  k_cvt_w<<<dim3(16, 16, 4), 256, 0, stream>>>(Wq, Wk, Wv, Wout, WqT, WkT, WvT, WoT);
  k_proj<<<dim3(8, 32, 3), 256, 0, stream>>>(Qb, Kb, Vb, WqT, WkT, WvT, bq, bk, bv, qh, kh, vT);
  k_attnA<<<dim3(8, 64), 256, 0, stream>>>(qh, kh, mask, attn, statM, statL);
  k_attnB<<<dim3(8, 64), 256, 0, stream>>>(vT, statM, statL, attn, ctx);
  k_outproj<<<dim3(8, 32), 256, 0, stream>>>(ctx, WoT, bout, Q, y);
  k_ln<<<dim3(4096), 256, 0, stream>>>(y, lng, lnb, outp);
}

// Round 2
// 556.370 us; speedup vs baseline: 1.1160x; 1.1160x over previous
//
#include <hip/hip_runtime.h>
#include <stdint.h>

typedef unsigned short u16;
typedef __bf16 bf8v __attribute__((ext_vector_type(8)));
typedef float f4v __attribute__((ext_vector_type(4)));

__device__ __forceinline__ u16 f2bf(float f) {
  uint32_t x = __float_as_uint(f);
  return (u16)((x + 0x7FFFu + ((x >> 16) & 1u)) >> 16);  // RNE, inputs are finite
}

// async global->LDS, 16B/lane, dest = wave-uniform base + lane*16
#define GLDS16(gp, lp)                                                        \
  __builtin_amdgcn_global_load_lds(                                           \
      (const __attribute__((address_space(1))) void*)(const void*)(gp),       \
      (__attribute__((address_space(3))) void*)(void*)(lp), 16, 0, 0)

// ---------------------------------------------------------------- cast fp32->bf16
__global__ __launch_bounds__(256) void k_cvt_act(const float* __restrict__ Q,
                                                 const float* __restrict__ K,
                                                 const float* __restrict__ V,
                                                 u16* __restrict__ Qb,
                                                 u16* __restrict__ Kb,
                                                 u16* __restrict__ Vb) {
  const float* src = blockIdx.z == 0 ? Q : (blockIdx.z == 1 ? K : V);
  u16* dst = blockIdx.z == 0 ? Qb : (blockIdx.z == 1 ? Kb : Vb);
  size_t i = ((size_t)blockIdx.x * 256 + threadIdx.x) * 4;
  float4 v = *(const float4*)(src + i);
  ushort4 o;
  o.x = f2bf(v.x); o.y = f2bf(v.y); o.z = f2bf(v.z); o.w = f2bf(v.w);
  *(ushort4*)(dst + i) = o;
}

// ------------------------------------------ transpose + cast weights: W[k][n] -> WT[n][k] bf16
__global__ __launch_bounds__(256) void k_cvt_w(const float* __restrict__ W0, const float* __restrict__ W1,
                                               const float* __restrict__ W2, const float* __restrict__ W3,
                                               u16* __restrict__ T0, u16* __restrict__ T1,
                                               u16* __restrict__ T2, u16* __restrict__ T3) {
  int z = blockIdx.z;
  const float* W = z == 0 ? W0 : z == 1 ? W1 : z == 2 ? W2 : W3;
  u16* T = z == 0 ? T0 : z == 1 ? T1 : z == 2 ? T2 : T3;
  __shared__ float tile[64][65];
  int n0 = blockIdx.x * 64, k0 = blockIdx.y * 64;
  int t = threadIdx.x;
#pragma unroll
  for (int i = 0; i < 16; ++i) {
    int idx = i * 256 + t;
    int rk = idx >> 6, cn = idx & 63;
    tile[rk][cn] = W[(size_t)(k0 + rk) * 1024 + n0 + cn];
  }
  __syncthreads();
#pragma unroll
  for (int i = 0; i < 16; ++i) {
    int idx = i * 256 + t;
    int rn = idx >> 6, ck = idx & 63;
    T[(size_t)(n0 + rn) * 1024 + k0 + ck] = f2bf(tile[ck][rn]);
  }
}

// ---------------------------------------------------------------- fused QKV projection GEMM
// A[4096][1024] bf16 @ WT[1024(n)][1024(k)] bf16 -> q/k: [b,h,s,64] bf16, v: [b,h,64,s] bf16
__global__ __launch_bounds__(256) void k_proj(const u16* __restrict__ Qb, const u16* __restrict__ Kb,
                                              const u16* __restrict__ Vb,
                                              const u16* __restrict__ WqT, const u16* __restrict__ WkT,
                                              const u16* __restrict__ WvT,
                                              const float* __restrict__ bq, const float* __restrict__ bk,
                                              const float* __restrict__ bv,
                                              u16* __restrict__ qh, u16* __restrict__ kh,
                                              u16* __restrict__ vT) {
  int z = blockIdx.z;
  const u16* A = z == 0 ? Qb : z == 1 ? Kb : Vb;
  const u16* Bt = z == 0 ? WqT : z == 1 ? WkT : WvT;
  const float* bias = z == 0 ? bq : z == 1 ? bk : bv;
  u16* out = z == 0 ? qh : z == 1 ? kh : vT;
  bool vtrans = (z == 2);

  __shared__ __align__(16) u16 sA[128 * 64];
  __shared__ __align__(16) u16 sB[128 * 64];

  int m0 = blockIdx.y * 128, n0 = blockIdx.x * 128;
  int t = threadIdx.x, w = t >> 6, lane = t & 63;
  int col = lane & 15, quad = lane >> 4;

  f4v zero4 = {0.f, 0.f, 0.f, 0.f};
  f4v acc[2][8];
#pragma unroll
  for (int tm = 0; tm < 2; ++tm)
#pragma unroll
    for (int tn = 0; tn < 8; ++tn) acc[tm][tn] = zero4;

  for (int kt = 0; kt < 1024; kt += 64) {
#pragma unroll
    for (int i = 0; i < 4; ++i) {
      int seg = i * 4 + w;
      int e = seg * 512 + lane * 8;
      int r = e >> 6, c = e & 63;
      GLDS16(A + (size_t)(m0 + r) * 1024 + kt + c, sA + seg * 512);
      GLDS16(Bt + (size_t)(n0 + r) * 1024 + kt + c, sB + seg * 512);
    }
    __syncthreads();
#pragma unroll
    for (int ks = 0; ks < 2; ++ks) {
      bf8v af[2], bfr[8];
#pragma unroll
      for (int tm = 0; tm < 2; ++tm)
        af[tm] = *(const bf8v*)&sA[(w * 32 + tm * 16 + col) * 64 + ks * 32 + quad * 8];
#pragma unroll
      for (int tn = 0; tn < 8; ++tn)
        bfr[tn] = *(const bf8v*)&sB[(tn * 16 + col) * 64 + ks * 32 + quad * 8];
#pragma unroll
      for (int tm = 0; tm < 2; ++tm)
#pragma unroll
        for (int tn = 0; tn < 8; ++tn)
          acc[tm][tn] = __builtin_amdgcn_mfma_f32_16x16x32_bf16(af[tm], bfr[tn], acc[tm][tn], 0, 0, 0);
    }
    __syncthreads();
  }

#pragma unroll
  for (int tm = 0; tm < 2; ++tm)
#pragma unroll
    for (int tn = 0; tn < 8; ++tn)
#pragma unroll
      for (int r = 0; r < 4; ++r) {
        int gr = m0 + w * 32 + tm * 16 + quad * 4 + r;
        int gc = n0 + tn * 16 + col;
        float v = acc[tm][tn][r] + bias[gc];
        int b = gr >> 10, s = gr & 1023;
        int h = gc >> 6, d = gc & 63;
        size_t off = vtrans ? ((size_t)((b * 16 + h) * 64 + d) * 1024 + s)
                            : ((size_t)((b * 16 + h) * 1024 + s) * 64 + d);
        out[off] = f2bf(v);
      }
}

// ---------------------------------------------------------------- attention pass A:
// QK^T -> row max + sumexp only (no score materialization)
__global__ __launch_bounds__(256) void k_attnA(const u16* __restrict__ qh, const u16* __restrict__ kh,
                                               const unsigned char* __restrict__ mask,
                                               float* __restrict__ statM, float* __restrict__ statL) {
  int qt = blockIdx.x, bh = blockIdx.y;
  int b = bh >> 4;
  __shared__ __align__(16) u16 sQ[128 * 64];
  __shared__ __align__(16) u16 sK[128 * 64];
  __shared__ __align__(16) unsigned char sM[128 * 128];
  int t = threadIdx.x, w = t >> 6, lane = t & 63;
  int col = lane & 15, quad = lane >> 4;

  {
    const u16* qbase = qh + ((size_t)bh * 1024 + qt * 128) * 64;
#pragma unroll
    for (int i = 0; i < 4; ++i) {
      int seg = i * 4 + w;
      GLDS16(qbase + seg * 512 + lane * 8, sQ + seg * 512);
    }
  }

  float mrun[2][4], lrun[2][4];
#pragma unroll
  for (int tm = 0; tm < 2; ++tm)
#pragma unroll
    for (int r = 0; r < 4; ++r) { mrun[tm][r] = -3.0e38f; lrun[tm][r] = 0.f; }

  f4v zero4 = {0.f, 0.f, 0.f, 0.f};

  for (int nc = 0; nc < 8; ++nc) {
    const u16* kbase = kh + ((size_t)bh * 1024 + nc * 128) * 64;
#pragma unroll
    for (int i = 0; i < 4; ++i) {
      int seg = i * 4 + w;
      GLDS16(kbase + seg * 512 + lane * 8, sK + seg * 512);
    }
    const unsigned char* mbase = mask + (size_t)b * 1024 * 1024 + (size_t)(qt * 128) * 1024 + nc * 128;
#pragma unroll
    for (int i = 0; i < 4; ++i) {
      int seg = i * 4 + w;
      int e = seg * 1024 + lane * 16;
      GLDS16(mbase + (size_t)(e >> 7) * 1024 + (e & 127), sM + seg * 1024);
    }
    __syncthreads();

    f4v acc[2][8];
#pragma unroll
    for (int tm = 0; tm < 2; ++tm)
#pragma unroll
      for (int tn = 0; tn < 8; ++tn) acc[tm][tn] = zero4;

#pragma unroll
    for (int ks = 0; ks < 2; ++ks) {
      bf8v af[2], bfr[8];
#pragma unroll
      for (int tm = 0; tm < 2; ++tm)
        af[tm] = *(const bf8v*)&sQ[(w * 32 + tm * 16 + col) * 64 + ks * 32 + quad * 8];
#pragma unroll
      for (int tn = 0; tn < 8; ++tn)
        bfr[tn] = *(const bf8v*)&sK[(tn * 16 + col) * 64 + ks * 32 + quad * 8];
#pragma unroll
      for (int tm = 0; tm < 2; ++tm)
#pragma unroll
        for (int tn = 0; tn < 8; ++tn)
          acc[tm][tn] = __builtin_amdgcn_mfma_f32_16x16x32_bf16(af[tm], bfr[tn], acc[tm][tn], 0, 0, 0);
    }

#pragma unroll
    for (int tm = 0; tm < 2; ++tm)
#pragma unroll
      for (int r = 0; r < 4; ++r) {
        int lrow = w * 32 + tm * 16 + quad * 4 + r;
        float vals[8];
        float cmax = -3.0e38f;
#pragma unroll
        for (int tn = 0; tn < 8; ++tn) {
          float v = acc[tm][tn][r] * 0.125f;
          if (sM[lrow * 128 + tn * 16 + col]) v = -1e9f;
          vals[tn] = v;
          cmax = fmaxf(cmax, v);
        }
#pragma unroll
        for (int off = 1; off < 16; off <<= 1) cmax = fmaxf(cmax, __shfl_xor(cmax, off));
        float csum = 0.f;
#pragma unroll
        for (int tn = 0; tn < 8; ++tn) csum += __expf(vals[tn] - cmax);
#pragma unroll
        for (int off = 1; off < 16; off <<= 1) csum += __shfl_xor(csum, off);
        float mo = mrun[tm][r];
        float mn = fmaxf(mo, cmax);
        lrun[tm][r] = lrun[tm][r] * __expf(mo - mn) + csum * __expf(cmax - mn);
        mrun[tm][r] = mn;
      }
    __syncthreads();
  }

  if (col == 0) {
#pragma unroll
    for (int tm = 0; tm < 2; ++tm)
#pragma unroll
      for (int r = 0; r < 4; ++r) {
        size_t idx = (size_t)bh * 1024 + qt * 128 + w * 32 + tm * 16 + quad * 4 + r;
        statM[idx] = mrun[tm][r];
        statL[idx] = lrun[tm][r];
      }
  }
}

// ---------------------------------------------------------------- attention pass B:
// recompute QK^T, p=exp(s-m)/l -> attn (only write), P@V -> ctx
// LDS: sQ 16K + sKV 16K (K then V) + sP 32K + sM 16K = 80KB -> 2 blocks/CU
__global__ __launch_bounds__(256) void k_attnB(const u16* __restrict__ qh, const u16* __restrict__ kh,
                                               const u16* __restrict__ vT,
                                               const unsigned char* __restrict__ mask,
                                               const float* __restrict__ statM,
                                               const float* __restrict__ statL,
                                               float* __restrict__ attn, u16* __restrict__ ctx) {
  int qt = blockIdx.x, bh = blockIdx.y, b = bh >> 4, h = bh & 15;
  __shared__ __align__(16) u16 sQ[128 * 64];
  __shared__ __align__(16) u16 sKV[128 * 64];   // K chunk [128][64], reused as V chunk [64][128]
  __shared__ __align__(16) u16 sP[128 * 128];
  __shared__ __align__(16) unsigned char sM[128 * 128];
  int t = threadIdx.x, w = t >> 6, lane = t & 63;
  int col = lane & 15, quad = lane >> 4;

  {
    const u16* qbase = qh + ((size_t)bh * 1024 + qt * 128) * 64;
#pragma unroll
    for (int i = 0; i < 4; ++i) {
      int seg = i * 4 + w;
      GLDS16(qbase + seg * 512 + lane * 8, sQ + seg * 512);
    }
  }

  float m_r[2][4], linv[2][4];
#pragma unroll
  for (int tm = 0; tm < 2; ++tm)
#pragma unroll
    for (int r = 0; r < 4; ++r) {
      size_t idx = (size_t)bh * 1024 + qt * 128 + w * 32 + tm * 16 + quad * 4 + r;
      m_r[tm][r] = statM[idx];
      linv[tm][r] = 1.0f / statL[idx];
    }

  f4v zero4 = {0.f, 0.f, 0.f, 0.f};
  f4v acc[2][4];
#pragma unroll
  for (int tm = 0; tm < 2; ++tm)
#pragma unroll
    for (int tn = 0; tn < 4; ++tn) acc[tm][tn] = zero4;

  for (int kc = 0; kc < 8; ++kc) {
    __syncthreads();  // prior PV finished reading sKV/sP in ALL waves before overwrite
    {
      const u16* kbase = kh + ((size_t)bh * 1024 + kc * 128) * 64;
#pragma unroll
      for (int i = 0; i < 4; ++i) {
        int seg = i * 4 + w;
        GLDS16(kbase + seg * 512 + lane * 8, sKV + seg * 512);
      }
      const unsigned char* mbase = mask + (size_t)b * 1024 * 1024 + (size_t)(qt * 128) * 1024 + kc * 128;
#pragma unroll
      for (int i = 0; i < 4; ++i) {
        int seg = i * 4 + w;
        int e = seg * 1024 + lane * 16;
        GLDS16(mbase + (size_t)(e >> 7) * 1024 + (e & 127), sM + seg * 1024);
      }
    }
    __syncthreads();  // K, mask (and first-iter sQ) resident

    // QK^T for this chunk
    float p[2][4][8];
    {
      f4v accs[2][8];
#pragma unroll
      for (int tm = 0; tm < 2; ++tm)
#pragma unroll
        for (int tn = 0; tn < 8; ++tn) accs[tm][tn] = zero4;
#pragma unroll
      for (int ks = 0; ks < 2; ++ks) {
        bf8v af[2], bfr[8];
#pragma unroll
        for (int tm = 0; tm < 2; ++tm)
          af[tm] = *(const bf8v*)&sQ[(w * 32 + tm * 16 + col) * 64 + ks * 32 + quad * 8];
#pragma unroll
        for (int tn = 0; tn < 8; ++tn)
          bfr[tn] = *(const bf8v*)&sKV[(tn * 16 + col) * 64 + ks * 32 + quad * 8];
#pragma unroll
        for (int tm = 0; tm < 2; ++tm)
#pragma unroll
          for (int tn = 0; tn < 8; ++tn)
            accs[tm][tn] = __builtin_amdgcn_mfma_f32_16x16x32_bf16(af[tm], bfr[tn], accs[tm][tn], 0, 0, 0);
      }
      // p = exp(scaled,masked score - m) / l ; stage bf16 p into sP
#pragma unroll
      for (int tm = 0; tm < 2; ++tm)
#pragma unroll
        for (int r = 0; r < 4; ++r) {
          int lrow = w * 32 + tm * 16 + quad * 4 + r;
#pragma unroll
          for (int tn = 0; tn < 8; ++tn) {
            float v = accs[tm][tn][r] * 0.125f;
            if (sM[lrow * 128 + tn * 16 + col]) v = -1e9f;
            float pp = __expf(v - m_r[tm][r]) * linv[tm][r];
            p[tm][r][tn] = pp;
            sP[lrow * 128 + tn * 16 + col] = f2bf(pp);
          }
        }
    }
    __syncthreads();  // sP visible; sKV(K) reads done

    {  // V chunk into the shared buffer
      const u16* vbase = vT + (size_t)bh * 64 * 1024 + kc * 128;
#pragma unroll
      for (int i = 0; i < 4; ++i) {
        int seg = i * 4 + w;
        int e = seg * 512 + lane * 8;
        GLDS16(vbase + (size_t)(e >> 7) * 1024 + (e & 127), sKV + seg * 512);
      }
    }
    __syncthreads();  // V resident

    // attn global stores overlap PV MFMA (no resource overlap)
#pragma unroll
    for (int tm = 0; tm < 2; ++tm)
#pragma unroll
      for (int r = 0; r < 4; ++r) {
        float* arow = attn + ((size_t)bh * 1024 + (size_t)qt * 128 + w * 32 + tm * 16 + quad * 4 + r) * 1024 + kc * 128;
#pragma unroll
        for (int tn = 0; tn < 8; ++tn) arow[tn * 16 + col] = p[tm][r][tn];
      }

#pragma unroll
    for (int ks = 0; ks < 4; ++ks) {
      bf8v af[2], bfr[4];
#pragma unroll
      for (int tm = 0; tm < 2; ++tm)
        af[tm] = *(const bf8v*)&sP[(w * 32 + tm * 16 + col) * 128 + ks * 32 + quad * 8];
#pragma unroll
      for (int tn = 0; tn < 4; ++tn)
        bfr[tn] = *(const bf8v*)&sKV[(tn * 16 + col) * 128 + ks * 32 + quad * 8];
#pragma unroll
      for (int tm = 0; tm < 2; ++tm)
#pragma unroll
        for (int tn = 0; tn < 4; ++tn)
          acc[tm][tn] = __builtin_amdgcn_mfma_f32_16x16x32_bf16(af[tm], bfr[tn], acc[tm][tn], 0, 0, 0);
    }
  }

#pragma unroll
  for (int tm = 0; tm < 2; ++tm)
#pragma unroll
    for (int tn = 0; tn < 4; ++tn)
#pragma unroll
      for (int r = 0; r < 4; ++r) {
        int token = qt * 128 + w * 32 + tm * 16 + quad * 4 + r;
        ctx[(size_t)(b * 1024 + token) * 1024 + h * 64 + tn * 16 + col] = f2bf(acc[tm][tn][r]);
      }
}

// ---------------------------------------------------------------- out projection + residual
__global__ __launch_bounds__(256) void k_outproj(const u16* __restrict__ ctx, const u16* __restrict__ WoT,
                                                 const float* __restrict__ bout,
                                                 const float* __restrict__ Qres, float* __restrict__ y) {
  __shared__ __align__(16) u16 sA[128 * 64];
  __shared__ __align__(16) u16 sB[128 * 64];
  int m0 = blockIdx.y * 128, n0 = blockIdx.x * 128;
  int t = threadIdx.x, w = t >> 6, lane = t & 63;
  int col = lane & 15, quad = lane >> 4;

  f4v zero4 = {0.f, 0.f, 0.f, 0.f};
  f4v acc[2][8];
#pragma unroll
  for (int tm = 0; tm < 2; ++tm)
#pragma unroll
    for (int tn = 0; tn < 8; ++tn) acc[tm][tn] = zero4;

  for (int kt = 0; kt < 1024; kt += 64) {
#pragma unroll
    for (int i = 0; i < 4; ++i) {
      int seg = i * 4 + w;
      int e = seg * 512 + lane * 8;
      int r = e >> 6, c = e & 63;
      GLDS16(ctx + (size_t)(m0 + r) * 1024 + kt + c, sA + seg * 512);
      GLDS16(WoT + (size_t)(n0 + r) * 1024 + kt + c, sB + seg * 512);
    }
    __syncthreads();
#pragma unroll
    for (int ks = 0; ks < 2; ++ks) {
      bf8v af[2], bfr[8];
#pragma unroll
      for (int tm = 0; tm < 2; ++tm)
        af[tm] = *(const bf8v*)&sA[(w * 32 + tm * 16 + col) * 64 + ks * 32 + quad * 8];
#pragma unroll
      for (int tn = 0; tn < 8; ++tn)
        bfr[tn] = *(const bf8v*)&sB[(tn * 16 + col) * 64 + ks * 32 + quad * 8];
#pragma unroll
      for (int tm = 0; tm < 2; ++tm)
#pragma unroll
        for (int tn = 0; tn < 8; ++tn)
          acc[tm][tn] = __builtin_amdgcn_mfma_f32_16x16x32_bf16(af[tm], bfr[tn], acc[tm][tn], 0, 0, 0);
    }
    __syncthreads();
  }

#pragma unroll
  for (int tm = 0; tm < 2; ++tm)
#pragma unroll
    for (int tn = 0; tn < 8; ++tn)
#pragma unroll
      for (int r = 0; r < 4; ++r) {
        int gr = m0 + w * 32 + tm * 16 + quad * 4 + r;
        int gc = n0 + tn * 16 + col;
        float v = acc[tm][tn][r] + bout[gc] + Qres[(size_t)gr * 1024 + gc];
        y[(size_t)gr * 1024 + gc] = v;
      }
}

// ---------------------------------------------------------------- layernorm
__global__ __launch_bounds__(256) void k_ln(const float* __restrict__ y, const float* __restrict__ g,
                                            const float* __restrict__ bb, float* __restrict__ out) {
  int r = blockIdx.x, t = threadIdx.x;
  const float* row = y + (size_t)r * 1024;
  float4 v = ((const float4*)row)[t];
  float s = v.x + v.y + v.z + v.w;
  float sq = v.x * v.x + v.y * v.y + v.z * v.z + v.w * v.w;
#pragma unroll
  for (int off = 1; off < 64; off <<= 1) {
    s += __shfl_xor(s, off);
    sq += __shfl_xor(sq, off);
  }
  __shared__ float ss[4], ssq[4];
  if ((t & 63) == 0) { ss[t >> 6] = s; ssq[t >> 6] = sq; }
  __syncthreads();
  s = ss[0] + ss[1] + ss[2] + ss[3];
  sq = ssq[0] + ssq[1] + ssq[2] + ssq[3];
  float mu = s * (1.f / 1024.f);
  float var = sq * (1.f / 1024.f) - mu * mu;
  float rst = rsqrtf(var + 1e-5f);
  float4 gg = ((const float4*)g)[t];
  float4 bv = ((const float4*)bb)[t];
  float4 o;
  o.x = (v.x - mu) * rst * gg.x + bv.x;
  o.y = (v.y - mu) * rst * gg.y + bv.y;
  o.z = (v.z - mu) * rst * gg.z + bv.z;
  o.w = (v.w - mu) * rst * gg.w + bv.w;
  ((float4*)(out + (size_t)r * 1024))[t] = o;
}

extern "C" void kernel_launch(void* const* d_in, const int* in_sizes, int n_in,
                              void* d_out, int out_size, void* d_ws, size_t ws_size,
                              hipStream_t stream) {
  (void)in_sizes; (void)n_in; (void)out_size; (void)ws_size;
  const float* Q = (const float*)d_in[0];
  const float* K = (const float*)d_in[1];
  const float* V = (const float*)d_in[2];
  const unsigned char* mask = (const unsigned char*)d_in[3];
  const float* Wq = (const float*)d_in[4];
  const float* bq = (const float*)d_in[5];
  const float* Wk = (const float*)d_in[6];
  const float* bk = (const float*)d_in[7];
  const float* Wv = (const float*)d_in[8];
  const float* bv = (const float*)d_in[9];
  const float* Wout = (const float*)d_in[10];
  const float* bout = (const float*)d_in[11];
  const float* lng = (const float*)d_in[12];
  const float* lnb = (const float*)d_in[13];

  u16* Qb = (u16*)d_ws;              // [4096][1024] bf16
  u16* Kb = Qb + 4194304;
  u16* Vb = Kb + 4194304;
  u16* WqT = Vb + 4194304;           // [1024][1024] bf16 (transposed)
  u16* WkT = WqT + 1048576;
  u16* WvT = WkT + 1048576;
  u16* WoT = WvT + 1048576;
  u16* qh = WoT + 1048576;           // [b,h,s,64] bf16
  u16* kh = qh + 4194304;            // [b,h,s,64]
  u16* vT = kh + 4194304;            // [b,h,64,s]
  u16* ctx = vT + 4194304;           // [4096][1024] bf16
  float* statM = (float*)(ctx + 4194304);
  float* statL = statM + 65536;
  float* y = statL + 65536;          // [4096][1024] f32

  float* outp = (float*)d_out;
  float* attn = outp + 4194304;      // [4][16][1024][1024] f32

  k_cvt_act<<<dim3(4096, 1, 3), 256, 0, stream>>>(Q, K, V, Qb, Kb, Vb);
  k_cvt_w<<<dim3(16, 16, 4), 256, 0, stream>>>(Wq, Wk, Wv, Wout, WqT, WkT, WvT, WoT);
  k_proj<<<dim3(8, 32, 3), 256, 0, stream>>>(Qb, Kb, Vb, WqT, WkT, WvT, bq, bk, bv, qh, kh, vT);
  k_attnA<<<dim3(8, 64), 256, 0, stream>>>(qh, kh, mask, statM, statL);
  k_attnB<<<dim3(8, 64), 256, 0, stream>>>(qh, kh, vT, mask, statM, statL, attn, ctx);
  k_outproj<<<dim3(8, 32), 256, 0, stream>>>(ctx, WoT, bout, Q, y);
  k_ln<<<dim3(4096), 256, 0, stream>>>(y, lng, lnb, outp);
}